// Round 4
// baseline (185.211 us; speedup 1.0000x reference)
//
#include <hip/hip_runtime.h>

// Problem constants (fixed by the reference).
constexpr int IN_CH = 4;
constexpr int KS    = 40;
constexpr int L_IN  = 8192;
constexpr int L_OUT = L_IN - KS + 1;   // 8153
constexpr int NF    = 600;
constexpr int BATCH = 32;
constexpr int CHUNK = 1024;            // outputs per block along L
constexpr int KPB   = 60;              // filters per block
constexpr int NKG   = NF / KPB;        // 10 k-groups
constexpr int XWIN  = CHUNK + KS;      // 1064 staged floats per channel
constexpr int XPAD  = 1196;            // g(1063)+1 : swizzled per-channel stride (R3 bug: was 1195)

// LDS swizzle: lane-stride-4 scalar reads land ~2 lanes/bank (free) instead of 8-way.
__device__ __forceinline__ int g(int l) { return l + (l >> 3); }

// ---- Kernel 1: extract the 2 nonzero taps of each filter into d_ws ----
// rec[k] = { c0*XPAD, p0, c1*XPAD, p1, w0, w1, 0, 0 }  (8 floats, ints bitcast)
__global__ void tap_kernel(const float* __restrict__ w, float* __restrict__ ws) {
    const int k = blockIdx.x * 256 + threadIdx.x;
    if (k >= NF) return;
    const float* wk = w + (size_t)k * IN_CH * KS;
    int n = 0; int pos[2] = {0, 0}; float val[2] = {0.f, 0.f};
    for (int i = 0; i < IN_CH * KS; ++i) {
        const float v = wk[i];
        if (v != 0.0f && n < 2) { pos[n] = i; val[n] = v; ++n; }
    }
    if (n == 1) { pos[1] = pos[0]; val[1] = 0.0f; }   // defensive
    float* r = ws + (size_t)k * 8;
    r[0] = __int_as_float((pos[0] / KS) * XPAD);
    r[1] = __int_as_float(pos[0] % KS);
    r[2] = __int_as_float((pos[1] / KS) * XPAD);
    r[3] = __int_as_float(pos[1] % KS);
    r[4] = val[0];
    r[5] = val[1];
    r[6] = 0.f; r[7] = 0.f;
}

// ---- Kernel 2: out[b,k,l] = w0*x[b,c0,l+p0] + w1*x[b,c1,l+p1] ----
// x chunk staged in swizzled LDS, reused by 60 filters. Stores are 64B-aligned
// float4 bursts (head/tail peeled per row) -> full-sector writes, no RFO.
__global__ __launch_bounds__(256) void fdc_main(const float* __restrict__ x,
                                                const float* __restrict__ ws,
                                                float* __restrict__ out) {
    const int base = blockIdx.x * CHUNK;
    const int k0   = blockIdx.y * KPB;
    const int b    = blockIdx.z;

    __shared__ float s_x[IN_CH * XPAD];   // 4*1196 floats; max index 3*1196+g(1063)=4783
    __shared__ int   s_b0[KPB], s_p0[KPB], s_b1[KPB], s_p1[KPB];
    __shared__ float s_w0[KPB], s_w1[KPB];

    // taps for this k-group
    if (threadIdx.x < KPB) {
        const float* r = ws + (size_t)(k0 + threadIdx.x) * 8;
        const float4 r0 = *reinterpret_cast<const float4*>(r);
        const float2 r1 = *reinterpret_cast<const float2*>(r + 4);
        s_b0[threadIdx.x] = __float_as_int(r0.x);
        s_p0[threadIdx.x] = __float_as_int(r0.y);
        s_b1[threadIdx.x] = __float_as_int(r0.z);
        s_p1[threadIdx.x] = __float_as_int(r0.w);
        s_w0[threadIdx.x] = r1.x;
        s_w1[threadIdx.x] = r1.y;
    }

    // stage x window (float4 global loads -> swizzled scalar LDS writes)
    const float* xb = x + (size_t)b * IN_CH * L_IN;
    const int nstage = min(XWIN, L_IN - base);
#pragma unroll
    for (int c = 0; c < IN_CH; ++c) {
        for (int l4 = threadIdx.x * 4; l4 < nstage; l4 += 1024) {
            const float4 v = *reinterpret_cast<const float4*>(xb + c * L_IN + base + l4);
            s_x[c * XPAD + g(l4 + 0)] = v.x;
            s_x[c * XPAD + g(l4 + 1)] = v.y;
            s_x[c * XPAD + g(l4 + 2)] = v.z;
            s_x[c * XPAD + g(l4 + 3)] = v.w;
        }
    }
    __syncthreads();

    const int nvalid = min(CHUNK, L_OUT - base);
    const int t = threadIdx.x;
    for (int kk = 0; kk < KPB; ++kk) {
        const int row  = k0 + kk;
        const int e0   = (b * NF + row) * L_OUT + base;   // element offset of chunk
        const int a    = (-e0) & 15;                      // head elems to 64B boundary
        const int n4   = (nvalid - a) >> 2;               // float4s (<= 256)
        const int tail = nvalid - a - (n4 << 2);          // <= 3
        const int   b0 = s_b0[kk], p0 = s_p0[kk];
        const int   b1 = s_b1[kk], p1 = s_p1[kk];
        const float w0 = s_w0[kk], w1 = s_w1[kk];
        float* orow = out + (size_t)e0;

        if (t < n4) {
            const int l  = a + t * 4;
            const int q0 = p0 + l, q1 = p1 + l;
            float4 v;
            v.x = w0 * s_x[b0 + g(q0 + 0)] + w1 * s_x[b1 + g(q1 + 0)];
            v.y = w0 * s_x[b0 + g(q0 + 1)] + w1 * s_x[b1 + g(q1 + 1)];
            v.z = w0 * s_x[b0 + g(q0 + 2)] + w1 * s_x[b1 + g(q1 + 2)];
            v.w = w0 * s_x[b0 + g(q0 + 3)] + w1 * s_x[b1 + g(q1 + 3)];
            *reinterpret_cast<float4*>(orow + l) = v;
        }
        // head [0,a) and tail [a+4*n4, nvalid): <= 18 scalars, threads 232..255
        const unsigned idx = (unsigned)t - 232u;
        if (idx < 24u) {
            int elem = -1;
            if ((int)idx < a)                 elem = (int)idx;
            else if ((int)idx - a < tail)     elem = (n4 << 2) + (int)idx;  // = a+4n4+(idx-a)
            if (elem >= 0)
                orow[elem] = w0 * s_x[b0 + g(p0 + elem)] + w1 * s_x[b1 + g(p1 + elem)];
        }
    }
}

extern "C" void kernel_launch(void* const* d_in, const int* in_sizes, int n_in,
                              void* d_out, int out_size, void* d_ws, size_t ws_size,
                              hipStream_t stream) {
    const float* x = (const float*)d_in[0];   // [32, 4, 8192] fp32
    const float* w = (const float*)d_in[1];   // [600, 4, 40]  fp32
    float*       o = (float*)d_out;           // [32, 600, 8153] fp32
    float*       ws = (float*)d_ws;           // 600*8 floats = 19.2 KB tap table

    tap_kernel<<<(NF + 255) / 256, 256, 0, stream>>>(w, ws);
    dim3 grid((L_OUT + CHUNK - 1) / CHUNK, NKG, BATCH);   // (8, 10, 32)
    fdc_main<<<grid, 256, 0, stream>>>(x, ws, o);
}

// Round 6
// 169.127 us; speedup vs baseline: 1.0951x; 1.0951x over previous
//
#include <hip/hip_runtime.h>

// Problem constants (fixed by the reference).
constexpr int IN_CH = 4;
constexpr int KS    = 40;
constexpr int L_IN  = 8192;
constexpr int L_OUT = L_IN - KS + 1;   // 8153
constexpr int NF    = 600;
constexpr int BATCH = 32;

typedef float floatx4 __attribute__((ext_vector_type(4)));   // native vec: OK for nontemporal builtins

// ---- Kernel 1: extract the 2 nonzero taps of each filter into d_ws ----
// rec[k] = float4{ off0, off1, w0, w1 }, offN = cN*L_IN + pN (ints bitcast).
__global__ void tap_kernel(const float* __restrict__ w, float* __restrict__ ws) {
    const int k = blockIdx.x * 256 + threadIdx.x;
    if (k >= NF) return;
    const float* wk = w + (size_t)k * IN_CH * KS;
    int n = 0; int off[2] = {0, 0}; float val[2] = {0.f, 0.f};
    for (int i = 0; i < IN_CH * KS; ++i) {
        const float v = wk[i];
        if (v != 0.0f && n < 2) { off[n] = (i / KS) * L_IN + (i % KS); val[n] = v; ++n; }
    }
    if (n == 1) { off[1] = off[0]; val[1] = 0.0f; }   // defensive
    float4 r;
    r.x = __int_as_float(off[0]);
    r.y = __int_as_float(off[1]);
    r.z = val[0];
    r.w = val[1];
    *reinterpret_cast<float4*>(ws + (size_t)k * 4) = r;
}

// ---- Kernel 2: one block per output row. The block writes one contiguous
// 32.6 KB span exactly once (64B-aligned float4 bursts, head/tail peeled once)
// -> machine-wide write pattern identical to fillBuffer (6.6 TB/s measured).
// x reads (2 scalars/output) come straight from L1/L2/L3 (x = 4 MB, resident);
// nontemporal stores keep the 611 MB write stream from evicting x out of L2.
__global__ __launch_bounds__(256) void fdc_row(const float* __restrict__ x,
                                               const float* __restrict__ ws,
                                               float* __restrict__ out) {
    const int row = blockIdx.x;            // 0..19199 == b*NF + k
    const int b   = row / NF;
    const int k   = row - b * NF;

    const float4 r   = *reinterpret_cast<const float4*>(ws + (size_t)k * 4);
    const float* xb  = x + (size_t)b * IN_CH * L_IN;
    const float* x0  = xb + __float_as_int(r.x);
    const float* x1  = xb + __float_as_int(r.y);
    const float  w0  = r.z, w1 = r.w;

    const size_t e0   = (size_t)row * L_OUT;   // element offset of row start
    float*       orow = out + e0;
    const int    a    = (int)((0u - (unsigned)e0) & 15u);  // head elems to 64B boundary
    const int    n4   = (L_OUT - a) >> 2;                  // aligned float4s (~2036)
    const int    tail = L_OUT - a - (n4 << 2);             // <= 3

    // bulk: 64B-aligned full-line nontemporal float4 stores
#pragma unroll 2
    for (int t = threadIdx.x; t < n4; t += 256) {
        const int l = a + t * 4;
        floatx4 v;
        v.x = w0 * x0[l + 0] + w1 * x1[l + 0];
        v.y = w0 * x0[l + 1] + w1 * x1[l + 1];
        v.z = w0 * x0[l + 2] + w1 * x1[l + 2];
        v.w = w0 * x0[l + 3] + w1 * x1[l + 3];
        __builtin_nontemporal_store(v, reinterpret_cast<floatx4*>(orow + l));
    }

    // head [0,a) + tail [a+4*n4, L_OUT): <= 18 scalars, once per block
    if (threadIdx.x < 24) {
        int elem = -1;
        if ((int)threadIdx.x < a) {
            elem = (int)threadIdx.x;
        } else {
            const int rr = (int)threadIdx.x - a;
            if (rr < tail) elem = a + (n4 << 2) + rr;
        }
        if (elem >= 0) orow[elem] = w0 * x0[elem] + w1 * x1[elem];
    }
}

extern "C" void kernel_launch(void* const* d_in, const int* in_sizes, int n_in,
                              void* d_out, int out_size, void* d_ws, size_t ws_size,
                              hipStream_t stream) {
    const float* x  = (const float*)d_in[0];   // [32, 4, 8192] fp32
    const float* w  = (const float*)d_in[1];   // [600, 4, 40]  fp32
    float*       o  = (float*)d_out;           // [32, 600, 8153] fp32
    float*       ws = (float*)d_ws;            // 600 * float4 tap table (9.6 KB)

    tap_kernel<<<(NF + 255) / 256, 256, 0, stream>>>(w, ws);
    fdc_row<<<NF * BATCH, 256, 0, stream>>>(x, ws, o);   // 19200 blocks, 1 row each
}